// Round 7
// baseline (318.577 us; speedup 1.0000x reference)
//
#include <hip/hip_runtime.h>

#define NP   8732
#define NB   32
#define NOBJ 16
#define NC   81
#define RPB  128
#define TPB  512
#define NROWS (NB * NP)               // 279424
#define CE_BLOCKS (NROWS / RPB)       // 2183
#define MCHUNKS 16
#define MCHUNK  546

__device__ __forceinline__ float sl1f(float x) {
  float d = fabsf(x);
  return d < 1.0f ? 0.5f * d * d : d - 0.5f;
}

__device__ __forceinline__ float iou_box(float tx0, float ty0, float tx1, float ty1,
                                         float ta, float px0, float py0, float px1,
                                         float py1, float pa) {
  float w = fminf(tx1, px1) - fmaxf(tx0, px0);
  float h = fminf(ty1, py1) - fmaxf(ty0, py0);
  w = fmaxf(w, 0.0f); h = fmaxf(h, 0.0f);
  float inter = w * h;
  return inter / (ta + pa - inter);
}

__device__ __forceinline__ float locloss(float tx0, float ty0, float tx1, float ty1,
                                         float4 pr, float4 ld) {
  float gx = ((tx0 + tx1) * 0.5f - pr.x) / (0.1f * pr.z);
  float gy = ((ty0 + ty1) * 0.5f - pr.y) / (0.1f * pr.w);
  float gw = logf((tx1 - tx0) / pr.z) / 0.2f;
  float gh = logf((ty1 - ty0) / pr.w) / 0.2f;
  return sl1f(ld.x - gx) + sl1f(ld.y - gy) + sl1f(ld.z - gw) + sl1f(ld.w - gh);
}

// ---- K1: per-truth argmax over priors, per-chunk plain stores (no init needed).
//      Block 0 also zeroes the accumulator region for K2. ----
__global__ __launch_bounds__(256) void kmatch(
    const float* __restrict__ targets, const float* __restrict__ priors,
    unsigned long long* __restrict__ bestPrChunk, int* __restrict__ zero_region)
{
  const int b = blockIdx.x >> 4, ch = blockIdx.x & 15;
  const int p0 = ch * MCHUNK, p1 = min(NP, p0 + MCHUNK);
  const int tid = threadIdx.x, w = tid >> 6, lane = tid & 63;
  if (blockIdx.x == 0 && tid < 72) zero_region[tid] = 0;
  __shared__ float tx0[NOBJ], ty0[NOBJ], tx1[NOBJ], ty1[NOBJ], ta[NOBJ];
  if (tid < NOBJ) {
    const float* tg = targets + (b * NOBJ + tid) * 5;
    float x0 = tg[0], y0 = tg[1], x1 = tg[2], y1 = tg[3];
    tx0[tid] = x0; ty0[tid] = y0; tx1[tid] = x1; ty1[tid] = y1;
    ta[tid] = (x1 - x0) * (y1 - y0);
  }
  __syncthreads();
  const int nb = w << 2;                     // this wave's 4 truths
  float bv[4]; int bp[4];
  #pragma unroll
  for (int j = 0; j < 4; ++j) { bv[j] = -1.0f; bp[j] = 0; }
  for (int p = p0 + lane; p < p1; p += 64) {
    float4 pr = reinterpret_cast<const float4*>(priors)[p];
    float px0 = pr.x - pr.z * 0.5f, py0 = pr.y - pr.w * 0.5f;
    float px1 = pr.x + pr.z * 0.5f, py1 = pr.y + pr.w * 0.5f;
    float pa = (px1 - px0) * (py1 - py0);
    #pragma unroll
    for (int j = 0; j < 4; ++j) {
      int n = nb + j;
      float iou = iou_box(tx0[n], ty0[n], tx1[n], ty1[n], ta[n],
                          px0, py0, px1, py1, pa);
      if (iou > bv[j]) { bv[j] = iou; bp[j] = p; }  // first occurrence: strict >
    }
  }
  #pragma unroll
  for (int j = 0; j < 4; ++j) {
    // key (iou_bits, NP-p): equal iou -> smaller p wins
    unsigned long long key =
        ((unsigned long long)__float_as_uint(bv[j]) << 32) | (unsigned)(NP - bp[j]);
    #pragma unroll
    for (int s = 1; s < 64; s <<= 1) {
      unsigned long long o = __shfl_xor(key, s, 64);
      key = o > key ? o : key;
    }
    if (lane == 0) bestPrChunk[(b * NOBJ + nb + j) * MCHUNKS + ch] = key;
  }
}

// ---- K2: staged compulsory pass (512 thr, 4 thr/row) + fused per-batch top-k ----
__global__ __launch_bounds__(512) void kce(
    const float* __restrict__ loc, const float* __restrict__ conf,
    const float* __restrict__ targets, const float* __restrict__ priors,
    const unsigned long long* __restrict__ bestPrChunk,
    float* __restrict__ mine, float* __restrict__ facc,
    int* __restrict__ iacc, int* __restrict__ num_pos,
    int* __restrict__ bticket, int* __restrict__ gticket,
    float* __restrict__ out)
{
  __shared__ float buf[RPB * NC];            // 41472 B
  __shared__ float stx0[32], sty0[32], stx1[32], sty1[32], sta[32];
  __shared__ int slab[32], sfp[32];
  __shared__ float redf[8], redc[8];
  __shared__ int redi[8], redj[8];
  __shared__ int redi2[2][8];
  __shared__ float redfa[8];
  __shared__ int redia[8];
  __shared__ int sRun[2];
  const int tid = threadIdx.x;
  const int r0 = blockIdx.x * RPB;
  const int b0 = r0 / NP;
  const int b1 = min(b0 + 1, NB - 1);
  const int bound = (b0 + 1) * NP;
  const bool span = (bound < r0 + RPB) && (b0 < NB - 1);

  // stage 2592 float4s: 5 per thread + 32-thread tail
  const float4* src = reinterpret_cast<const float4*>(conf) + (size_t)r0 * NC / 4;
  float4* buf4 = reinterpret_cast<float4*>(buf);
  float4 tmp[5];
  #pragma unroll
  for (int i = 0; i < 5; ++i) tmp[i] = src[tid + i * TPB];
  if (tid < 32) {                            // truths for (up to) 2 batches
    int bsel = (tid >> 4) ? b1 : b0;
    int n = tid & 15;
    const float* tg = targets + (bsel * NOBJ + n) * 5;
    float x0 = tg[0], y0 = tg[1], x1 = tg[2], y1 = tg[3];
    stx0[tid] = x0; sty0[tid] = y0; stx1[tid] = x1; sty1[tid] = y1;
    sta[tid] = (x1 - x0) * (y1 - y0);
    slab[tid] = (int)tg[4];
    const unsigned long long* kp = bestPrChunk + (bsel * NOBJ + n) * MCHUNKS;
    unsigned long long key = 0ull;
    #pragma unroll
    for (int c = 0; c < MCHUNKS; ++c) {
      unsigned long long o = kp[c];
      key = o > key ? o : key;
    }
    sfp[tid] = NP - (int)(key & 0xFFFFFFFFull);
  }
  #pragma unroll
  for (int i = 0; i < 5; ++i) buf4[tid + i * TPB] = tmp[i];
  if (tid < 32) buf4[2560 + tid] = src[2560 + tid];
  __syncthreads();

  const int rr = tid >> 2, q = tid & 3;      // row-in-block, quarter
  const int r = r0 + rr;
  const int brow = (r >= bound) ? 1 : 0;
  const int bb = brow << 4;
  const int p = r - (brow ? b1 : b0) * NP;

  float4 pr = reinterpret_cast<const float4*>(priors)[p];
  float px0 = pr.x - pr.z * 0.5f, py0 = pr.y - pr.w * 0.5f;
  float px1 = pr.x + pr.z * 0.5f, py1 = pr.y + pr.w * 0.5f;
  float pa = (px1 - px0) * (py1 - py0);
  // 4 truths per thread: best-IoU (first occurrence) + forced match (last wins)
  float v = -1.0f; int bn = 0; int fm = -1;
  #pragma unroll
  for (int j = 0; j < 4; ++j) {
    int n = q * 4 + j;
    float iou = iou_box(stx0[bb + n], sty0[bb + n], stx1[bb + n], sty1[bb + n],
                        sta[bb + n], px0, py0, px1, py1, pa);
    if (iou > v) { v = iou; bn = n; }
    if (sfp[bb + n] == p) fm = n;
  }
  #pragma unroll
  for (int s = 1; s < 4; s <<= 1) {          // combine across the 4 lanes of the row
    float ov = __shfl_xor(v, s, 64);
    int   on = __shfl_xor(bn, s, 64);
    int  ofm = __shfl_xor(fm, s, 64);
    bool better = (ov > v) || (ov == v && on < bn);
    if (better) { v = ov; bn = on; }
    fm = max(fm, ofm);
  }
  int nm, ct;
  if (fm >= 0) { nm = fm; ct = slab[bb + fm] + 1; }
  else         { nm = bn; ct = (v < 0.5f) ? 0 : (slab[bb + bn] + 1); }

  // lse without max pass (|conf| ~ N(0,1); fp32-safe): 21/20/20/20 split
  const int off = (q == 0) ? 0 : 21 + 20 * (q - 1);
  const int cnt = (q == 0) ? 21 : 20;
  const float* rowp = buf + rr * NC + off;
  float se = 0.0f;
  for (int j = 0; j < cnt; ++j) se += expf(rowp[j]);
  #pragma unroll
  for (int s = 1; s < 4; s <<= 1) se += __shfl_xor(se, s, 64);
  float ce = logf(se) - buf[rr * NC + ct];

  float lsum = 0.0f, cep = 0.0f; int pc0 = 0, pc1 = 0;
  if (q == 0) {
    if (ct > 0) {
      mine[r] = 0.0f;
      cep = ce;
      if (brow) pc1 = 1; else pc0 = 1;
      float4 ld = reinterpret_cast<const float4*>(loc)[r];
      lsum = locloss(stx0[bb + nm], sty0[bb + nm], stx1[bb + nm], sty1[bb + nm],
                     pr, ld);
    } else {
      mine[r] = ce;
    }
  }
  #pragma unroll
  for (int s = 32; s >= 1; s >>= 1) {
    lsum += __shfl_xor(lsum, s, 64);
    cep  += __shfl_xor(cep, s, 64);
    pc0  += __shfl_xor(pc0, s, 64);
    pc1  += __shfl_xor(pc1, s, 64);
  }
  if ((tid & 63) == 0) {
    redf[tid >> 6] = lsum; redc[tid >> 6] = cep;
    redi[tid >> 6] = pc0;  redj[tid >> 6] = pc1;
  }
  __syncthreads();
  if (tid == 0) {
    float lt = 0.0f, cc = 0.0f; int p0s = 0, p1s = 0;
    #pragma unroll
    for (int w = 0; w < 8; ++w) { lt += redf[w]; cc += redc[w]; p0s += redi[w]; p1s += redj[w]; }
    if (lt != 0.0f) atomicAdd(&facc[0], lt);
    if (cc != 0.0f) atomicAdd(&facc[1], cc);
    if (p0s) atomicAdd(&num_pos[b0], p0s);
    if (p1s) atomicAdd(&num_pos[b1], p1s);
    if (p0s + p1s) atomicAdd(&iacc[0], p0s + p1s);
    // release our mine/facc writes, then tick batch tickets
    __threadfence();
    int c0 = atomicAdd(&bticket[b0], 1) + 1;
    int fb = (b0 * NP) / RPB, lb = ((b0 + 1) * NP - 1) / RPB;
    sRun[0] = (c0 == lb - fb + 1) ? b0 : -1;
    sRun[1] = -1;
    if (span) {
      int c1 = atomicAdd(&bticket[b1], 1) + 1;
      int fb1 = (b1 * NP) / RPB, lb1 = ((b1 + 1) * NP - 1) / RPB;
      sRun[1] = (c1 == lb1 - fb1 + 1) ? b1 : -1;
    }
  }
  __syncthreads();

  // fused top-k for any batch this block completed (0, 1, or 2 of them)
  for (int si = 0; si < 2; ++si) {
    const int bt = sRun[si];
    if (bt < 0) continue;
    __threadfence();                          // acquire: see other blocks' mine stores
    const float* msrc = mine + (size_t)bt * NP;
    float rv[18];
    #pragma unroll
    for (int i = 0; i < 18; ++i) {
      int idx = tid + (i << 9);
      rv[i] = (idx < NP) ? msrc[idx] : -1.0f; // sentinel never > thr (thr >= 0)
    }
    int k = 3 * atomicAdd(&num_pos[bt], 0);
    if (k > NP - 1) k = NP - 1;
    float tot = 0.0f;
    const int wid = tid >> 6, lane = tid & 63;
    if (k > 0) {
      unsigned lo = 0u, hi = 0x7f800000u; int par = 0;
      while (lo < hi) {
        unsigned mid = lo + ((hi - lo) >> 1);
        float thr = __uint_as_float(mid);
        int c = 0;
        #pragma unroll
        for (int i = 0; i < 18; ++i) c += (rv[i] > thr) ? 1 : 0;
        #pragma unroll
        for (int s = 32; s >= 1; s >>= 1) c += __shfl_xor(c, s, 64);
        if (lane == 0) redi2[par][wid] = c;
        __syncthreads();
        int t = 0;
        #pragma unroll
        for (int w = 0; w < 8; ++w) t += redi2[par][w];
        par ^= 1;
        if (t < k) hi = mid; else lo = mid + 1;
      }
      float vk = __uint_as_float(lo);
      int cgt = 0; float s = 0.0f;
      #pragma unroll
      for (int i = 0; i < 18; ++i) {
        float val = rv[i];
        if (val > vk) { ++cgt; s += val; }
      }
      #pragma unroll
      for (int sh = 32; sh >= 1; sh >>= 1) {
        cgt += __shfl_xor(cgt, sh, 64);
        s   += __shfl_xor(s,   sh, 64);
      }
      __syncthreads();
      if (lane == 0) { redia[wid] = cgt; redfa[wid] = s; }
      __syncthreads();
      if (tid == 0) {
        int c = 0; float tt = 0.0f;
        #pragma unroll
        for (int w = 0; w < 8; ++w) { c += redia[w]; tt += redfa[w]; }
        tot = tt + (float)(k - c) * vk;
      }
    }
    if (tid == 0) {
      atomicAdd(&facc[2], tot);
      __threadfence();
      int g = atomicAdd(gticket, 1);
      if (g == NB - 1) {                      // 32nd batch completion: finalize
        float f0 = atomicAdd(&facc[0], 0.0f);
        float f1 = atomicAdd(&facc[1], 0.0f);
        float f2 = atomicAdd(&facc[2], 0.0f);
        float N = (float)atomicAdd(&iacc[0], 0);
        out[0] = f0 / N;                      // LOC_WEIGHT = 1.0
        out[1] = (f1 + f2) / N;
      }
    }
    __syncthreads();
  }
}

extern "C" void kernel_launch(void* const* d_in, const int* in_sizes, int n_in,
                              void* d_out, int out_size, void* d_ws, size_t ws_size,
                              hipStream_t stream) {
  const float* loc     = (const float*)d_in[0];
  const float* conf    = (const float*)d_in[1];
  const float* targets = (const float*)d_in[2];
  const float* priors  = (const float*)d_in[3];
  float* out = (float*)d_out;

  // workspace layout (bytes):
  //   0    facc[4]          16  iacc         20  gticket
  //   32   num_pos[32]      160 bticket[32]      (zero region = ints [0,72))
  //   512  bestPrChunk[NB*NOBJ*MCHUNKS] u64 (65536)
  //   66048 mine[NROWS] floats
  char* ws = (char*)d_ws;
  float* facc    = (float*)ws;
  int*   iacc    = (int*)(ws + 16);
  int*   gticket = (int*)(ws + 20);
  int*   num_pos = (int*)(ws + 32);
  int*   bticket = (int*)(ws + 160);
  int*   zero_region = (int*)ws;
  unsigned long long* bestPrChunk = (unsigned long long*)(ws + 512);
  float* mine    = (float*)(ws + 66048);

  hipLaunchKernelGGL(kmatch, dim3(512), dim3(256), 0, stream,
                     targets, priors, bestPrChunk, zero_region);
  hipLaunchKernelGGL(kce, dim3(CE_BLOCKS), dim3(TPB), 0, stream,
                     loc, conf, targets, priors, bestPrChunk,
                     mine, facc, iacc, num_pos, bticket, gticket, out);
}